// Round 2
// baseline (677.774 us; speedup 1.0000x reference)
//
#include <hip/hip_runtime.h>
#include <math.h>

typedef __bf16 bf16;
typedef __bf16 bf16x8 __attribute__((ext_vector_type(8)));
typedef __bf16 bf16x4 __attribute__((ext_vector_type(4)));
typedef float f32x4 __attribute__((ext_vector_type(4)));
typedef __bf16 bf16x8_a __attribute__((ext_vector_type(8), __may_alias__));
typedef __bf16 bf16_a __attribute__((__may_alias__));

constexpr int BATCH = 2;
constexpr int SEQ   = 2048;
constexpr int HID   = 2048;
constexpr int NHEAD = 16;
constexpr int NKV   = 8;
constexpr int HD    = 128;
constexpr int MROWS = BATCH * SEQ; // 4096

#define DEVINL __device__ __forceinline__

DEVINL void async16(void* l, const void* g) {
  __builtin_amdgcn_global_load_lds((const __attribute__((address_space(1))) void*)g,
                                   (__attribute__((address_space(3))) void*)l, 16, 0, 0);
}

DEVINL f32x4 mfma16(bf16x8 a, bf16x8 b, f32x4 c) {
  return __builtin_amdgcn_mfma_f32_16x16x32_bf16(a, b, c, 0, 0, 0);
}

DEVINL f32x4 fzero4() { f32x4 z; z[0] = 0.f; z[1] = 0.f; z[2] = 0.f; z[3] = 0.f; return z; }

DEVINL float ex2(float x) {
#if __has_builtin(__builtin_amdgcn_exp2f)
  return __builtin_amdgcn_exp2f(x);
#else
  return __expf(x * 0.6931471805599453f);
#endif
}
DEVINL float rcp1(float x) {
#if __has_builtin(__builtin_amdgcn_rcpf)
  return __builtin_amdgcn_rcpf(x);
#else
  return 1.0f / x;
#endif
}

// ---------------- elementwise cast f32 -> bf16 ----------------
__global__ __launch_bounds__(256) void cast_f32_bf16(const float* __restrict__ x,
                                                     bf16* __restrict__ y, int n) {
  int i = (blockIdx.x * 256 + threadIdx.x) * 4;
  if (i + 3 < n) {
    float4 v = *(const float4*)(x + i);
    bf16x4 o;
    o[0] = (bf16)v.x; o[1] = (bf16)v.y; o[2] = (bf16)v.z; o[3] = (bf16)v.w;
    *(bf16x4*)(y + i) = o;
  }
}

// ---------------- W transpose f32[K][N] -> bf16 WT[N][K] ----------------
__global__ __launch_bounds__(256) void wtrans(const float* __restrict__ W,
                                              bf16* __restrict__ WT, int K, int N) {
  __shared__ bf16 t[64][65];
  int n0 = blockIdx.x * 64, k0 = blockIdx.y * 64;
  for (int i = threadIdx.x; i < 4096; i += 256) {
    int r = i >> 6, c = i & 63;
    t[r][c] = (bf16)W[(size_t)(k0 + r) * N + n0 + c];
  }
  __syncthreads();
  for (int i = threadIdx.x; i < 4096; i += 256) {
    int r = i >> 6, c = i & 63;
    WT[(size_t)(n0 + r) * K + k0 + c] = t[c][r];
  }
}

// ---------------- V[b*S+s][kvh*128+d] -> VT[(b*8+kvh)*128+d][s] ----------------
__global__ __launch_bounds__(256) void vtrans(const bf16* __restrict__ V, bf16* __restrict__ VT) {
  __shared__ bf16 t[64][65];
  int s0 = blockIdx.x * 64, d0 = blockIdx.y * 64;
  int bh = blockIdx.z, b = bh >> 3, kvh = bh & 7;
  for (int i = threadIdx.x; i < 4096; i += 256) {
    int r = i >> 6, c = i & 63;
    t[r][c] = V[(size_t)(b * SEQ + s0 + r) * (NKV * HD) + kvh * HD + d0 + c];
  }
  __syncthreads();
  for (int i = threadIdx.x; i < 4096; i += 256) {
    int r = i >> 6, c = i & 63;
    VT[((size_t)bh * HD + d0 + r) * SEQ + s0 + c] = t[c][r];
  }
}

// ---------------- RoPE tables: cos/sin [SEQ][64] ----------------
__global__ void rope_tab(float* __restrict__ ct, float* __restrict__ st) {
  int s = blockIdx.x, d = threadIdx.x;
  float freq = powf(10000.0f, -(float)d * (1.0f / 64.0f));
  float a = (float)s * freq;
  ct[s * 64 + d] = cosf(a);
  st[s * 64 + d] = sinf(a);
}

// ---------------- GEMM: C = A[M,K] @ BT[N,K]^T ----------------
// EPI: 0 = bf16 store, 1 = RoPE + bf16 store, 2 = f32 store
template <int EPI>
__global__ __launch_bounds__(256) void gemm_bf16k(const bf16* __restrict__ A,
                                                  const bf16* __restrict__ BT,
                                                  void* __restrict__ Cout, int M, int N, int K,
                                                  const float* __restrict__ ct,
                                                  const float* __restrict__ st) {
  __shared__ alignas(16) char ldsA[16384];
  __shared__ alignas(16) char ldsB[16384];
  const int tid = threadIdx.x;
  const int lane = tid & 63;
  const int w = tid >> 6;
  const int l15 = lane & 15;
  const int l4 = lane >> 4;
  // bijective XCD swizzle (nwg % 8 == 0 for all our grids)
  const int gx = gridDim.x;
  const int nwg = gx * gridDim.y;
  int id = blockIdx.y * gx + blockIdx.x;
  id = (id & 7) * (nwg >> 3) + (id >> 3);
  const int row0 = (id / gx) * 128;
  const int col0 = (id % gx) * 128;

  f32x4 acc[2][8];
#pragma unroll
  for (int mt = 0; mt < 2; mt++)
#pragma unroll
    for (int nt = 0; nt < 8; nt++) acc[mt][nt] = fzero4();

  const int ciB = w * 64 + lane;
  const int nk = K >> 6;
  for (int kt = 0; kt < nk; ++kt) {
    const int k0 = kt << 6;
    __syncthreads();
#pragma unroll
    for (int j = 0; j < 4; j++) {
      int ci = j * 256 + ciB;
      int r = ci >> 3, ps = ci & 7, ls = ps ^ (r & 7);
      char* dstA = ldsA + (j * 256 + w * 64) * 16;
      char* dstB = ldsB + (j * 256 + w * 64) * 16;
      async16(dstA, A + (size_t)(row0 + r) * K + k0 + ls * 8);
      async16(dstB, BT + (size_t)(col0 + r) * K + k0 + ls * 8);
    }
    asm volatile("s_waitcnt vmcnt(0)" ::: "memory");
    __syncthreads();

    bf16x8 af[2][2];
#pragma unroll
    for (int mt = 0; mt < 2; mt++)
#pragma unroll
      for (int kc = 0; kc < 2; kc++) {
        int r = w * 32 + mt * 16 + l15;
        int off = ((r << 7) + ((kc * 4 + l4) << 4)) ^ ((r & 7) << 4);
        af[mt][kc] = *(const bf16x8_a*)(ldsA + off);
      }
#pragma unroll
    for (int nt = 0; nt < 8; nt++) {
#pragma unroll
      for (int kc = 0; kc < 2; kc++) {
        int r = nt * 16 + l15;
        int off = ((r << 7) + ((kc * 4 + l4) << 4)) ^ ((r & 7) << 4);
        bf16x8 bfr = *(const bf16x8_a*)(ldsB + off);
        acc[0][nt] = mfma16(af[0][kc], bfr, acc[0][nt]);
        acc[1][nt] = mfma16(af[1][kc], bfr, acc[1][nt]);
      }
    }
  }

#pragma unroll
  for (int mt = 0; mt < 2; mt++)
#pragma unroll
    for (int nt = 0; nt < 8; nt++)
#pragma unroll
      for (int rg = 0; rg < 4; rg++) {
        int row = row0 + w * 32 + mt * 16 + l4 * 4 + rg;
        int col = col0 + nt * 16 + l15;
        float v = acc[mt][nt][rg];
        if (EPI == 2) {
          ((float*)Cout)[(size_t)row * N + col] = v;
        } else if (EPI == 0) {
          ((bf16*)Cout)[(size_t)row * N + col] = (bf16)v;
        } else {
          int d = col & 127;
          int s = row & (SEQ - 1);
          int ntp = (nt < 4) ? nt + 4 : nt - 4;
          float pv = (nt < 4) ? -acc[mt][ntp][rg] : acc[mt][ntp][rg];
          float cc = ct[s * 64 + (d & 63)];
          float ss = st[s * 64 + (d & 63)];
          ((bf16*)Cout)[(size_t)row * N + col] = (bf16)(v * cc + pv * ss);
        }
      }
}

// ---------------- Flash attention v2 ----------------
// grid (qt=32, h=16, b=2) swizzled, 256 thr / 4 waves; wave = 16 q-rows.
// No barriers; K/V fragments read directly from global (L2-resident);
// fixed-max softmax (softcap bounds scores to +/-50); P via per-wave swizzled LDS.
__global__ __launch_bounds__(256) void attn2(const bf16* __restrict__ Q,
                                             const bf16* __restrict__ Kg,
                                             const bf16* __restrict__ VTg,
                                             bf16* __restrict__ O) {
  __shared__ alignas(16) char ldsP[8192];
  const int tid = threadIdx.x, lane = tid & 63, w = tid >> 6;
  const int l15 = lane & 15, l4 = lane >> 4;

  const int nx = gridDim.x, ny = gridDim.y;
  const int nwg = nx * ny * gridDim.z;  // 1024
  int id = (blockIdx.z * ny + blockIdx.y) * nx + blockIdx.x;
  id = (id & 7) * (nwg >> 3) + (id >> 3);
  const int qt = id % nx; id /= nx;
  const int h = id % ny; const int b = id / ny;
  const int kvh = h >> 1;
  const int rowQ0 = b * SEQ + qt * 64 + w * 16;

  // Q A-fragments (row = l15, k = kc*32 + l4*8 + j)
  bf16x8 qf[4];
  const bf16* qp = Q + (size_t)(rowQ0 + l15) * (NHEAD * HD) + h * HD + l4 * 8;
#pragma unroll
  for (int kc = 0; kc < 4; kc++) qf[kc] = *(const bf16x8_a*)(qp + kc * 32);

  f32x4 o[8];
#pragma unroll
  for (int dt = 0; dt < 8; dt++) o[dt] = fzero4();
  float lsum[4] = {0.f, 0.f, 0.f, 0.f};

  // per-iter advancing bases (per-lane row/slice folded in once)
  const bf16* kb = Kg + ((size_t)(b * SEQ) + l15) * (NKV * HD) + kvh * HD + l4 * 8;
  const bf16* vb = VTg + ((size_t)(b * NKV + kvh) * HD + l15) * SEQ + l4 * 8;

  char* myP = ldsP + w * 2048;
  // P LDS layout: addr(q,kv) = q*128 + kv*2, XOR ((q&7)<<4)
  const int rbase = ((l15 << 7) + (l4 << 4)) ^ ((l15 & 7) << 4);  // read base (kc via ^kc<<6)
  const int wb0 = (l4 << 9) + (l15 << 1);                         // q = l4*4 (+rg), kv-col = l15
  const int xvb = (l4 & 1) << 6;                                  // (q&7) bit2 as q = 4*l4+rg

  const float C1 = 5.100874372587525e-3f;   // 2*log2e/(50*sqrt(128))
  const float C2 = -144.26950408889634f;    // -100*log2e
  const float C3 = 72.13475204444817f;      // 50*log2e

  for (int t = 0; t < SEQ / 64; ++t) {
    // ---- QK^T: S[16 q][64 kv], K as B-fragments straight from global ----
    f32x4 sc[4];
#pragma unroll
    for (int nt = 0; nt < 4; nt++) sc[nt] = fzero4();
#pragma unroll
    for (int nt = 0; nt < 4; nt++) {
#pragma unroll
      for (int kc = 0; kc < 4; kc++) {
        bf16x8 kf = *(const bf16x8_a*)(kb + nt * 16 * (NKV * HD) + kc * 32);
        sc[nt] = mfma16(qf[kc], kf, sc[nt]);
      }
    }

    // ---- softcap + exp (fixed max: p = exp(50*tanh(s/(sqrt(128)*50)))) ----
#pragma unroll
    for (int nt = 0; nt < 4; nt++) {
#pragma unroll
      for (int rg = 0; rg < 4; rg++) {
        float s = sc[nt][rg];
        float u = ex2(s * C1);
        float r = rcp1(1.0f + u);
        float p = ex2(fmaf(C2, r, C3));
        lsum[rg] += p;
        int waddr = (wb0 + rg * 128 + nt * 32) ^ xvb ^ (rg << 4);
        *(bf16_a*)(myP + waddr) = (bf16)p;
      }
    }
    asm volatile("s_waitcnt lgkmcnt(0)" ::: "memory");

    // ---- PV: O += P[16 q][64 kv] @ V[64 kv][128 d] ----
    bf16x8 pa[2];
#pragma unroll
    for (int kc = 0; kc < 2; kc++)
      pa[kc] = *(const bf16x8_a*)(myP + (rbase ^ (kc << 6)));
#pragma unroll
    for (int dt = 0; dt < 8; dt++) {
#pragma unroll
      for (int kc = 0; kc < 2; kc++) {
        bf16x8 vf = *(const bf16x8_a*)(vb + (size_t)dt * 16 * SEQ + kc * 32);
        o[dt] = mfma16(pa[kc], vf, o[dt]);
      }
    }

    kb += 64 * (NKV * HD);
    vb += 64;
  }

  // final row-sum reduce across the 16-lane column groups
#pragma unroll
  for (int rg = 0; rg < 4; rg++) {
    float v = lsum[rg];
    v += __shfl_xor(v, 1);
    v += __shfl_xor(v, 2);
    v += __shfl_xor(v, 4);
    v += __shfl_xor(v, 8);
    lsum[rg] = 1.0f / v;
  }

#pragma unroll
  for (int rg = 0; rg < 4; rg++) {
    int row = rowQ0 + l4 * 4 + rg;
#pragma unroll
    for (int dt = 0; dt < 8; dt++) {
      int col = h * HD + dt * 16 + l15;
      O[(size_t)row * (NHEAD * HD) + col] = (bf16)(o[dt][rg] * lsum[rg]);
    }
  }
}

extern "C" void kernel_launch(void* const* d_in, const int* in_sizes, int n_in,
                              void* d_out, int out_size, void* d_ws, size_t ws_size,
                              hipStream_t stream) {
  const float* X  = (const float*)d_in[0];
  const float* Wq = (const float*)d_in[1];
  const float* Wk = (const float*)d_in[2];
  const float* Wv = (const float*)d_in[3];
  const float* Wo = (const float*)d_in[4];
  float* out = (float*)d_out;

  char* ws = (char*)d_ws;
  size_t off = 0;
  auto alloc = [&](size_t bytes) {
    void* p = ws + off;
    off += (bytes + 255) & ~(size_t)255;
    return p;
  };
  bf16* Xb  = (bf16*)alloc((size_t)MROWS * HID * 2);
  bf16* WqT = (bf16*)alloc((size_t)2048 * 2048 * 2);
  bf16* WkT = (bf16*)alloc((size_t)1024 * 2048 * 2);
  bf16* WvT = (bf16*)alloc((size_t)1024 * 2048 * 2);
  bf16* WoT = (bf16*)alloc((size_t)2048 * 2048 * 2);
  bf16* Qb  = (bf16*)alloc((size_t)MROWS * 2048 * 2);
  bf16* Kb  = (bf16*)alloc((size_t)MROWS * 1024 * 2);
  bf16* Vb  = (bf16*)alloc((size_t)MROWS * 1024 * 2);
  bf16* VTb = (bf16*)alloc((size_t)16 * 128 * 2048 * 2);
  bf16* AOb = (bf16*)alloc((size_t)MROWS * 2048 * 2);
  float* ct = (float*)alloc((size_t)SEQ * 64 * 4);
  float* st = (float*)alloc((size_t)SEQ * 64 * 4);

  cast_f32_bf16<<<(MROWS * HID) / 1024, 256, 0, stream>>>(X, Xb, MROWS * HID);
  wtrans<<<dim3(32, 32), 256, 0, stream>>>(Wq, WqT, 2048, 2048);
  wtrans<<<dim3(16, 32), 256, 0, stream>>>(Wk, WkT, 2048, 1024);
  wtrans<<<dim3(16, 32), 256, 0, stream>>>(Wv, WvT, 2048, 1024);
  wtrans<<<dim3(32, 32), 256, 0, stream>>>(Wo, WoT, 2048, 2048);
  rope_tab<<<SEQ, 64, 0, stream>>>(ct, st);
  gemm_bf16k<1><<<dim3(16, 32), 256, 0, stream>>>(Xb, WqT, Qb, MROWS, 2048, 2048, ct, st);
  gemm_bf16k<1><<<dim3(8, 32), 256, 0, stream>>>(Xb, WkT, Kb, MROWS, 1024, 2048, ct, st);
  gemm_bf16k<0><<<dim3(8, 32), 256, 0, stream>>>(Xb, WvT, Vb, MROWS, 1024, 2048, nullptr, nullptr);
  vtrans<<<dim3(32, 2, 16), 256, 0, stream>>>(Vb, VTb);
  attn2<<<dim3(32, 16, 2), 256, 0, stream>>>(Qb, Kb, VTb, AOb);
  gemm_bf16k<2><<<dim3(16, 32), 256, 0, stream>>>(AOb, WoT, out, MROWS, 2048, 2048, nullptr, nullptr);

  (void)in_sizes; (void)n_in; (void)out_size; (void)ws_size;
}

// Round 3
// 328.999 us; speedup vs baseline: 2.0601x; 2.0601x over previous
//
#include <hip/hip_runtime.h>
#include <math.h>

typedef __bf16 bf16;
typedef __bf16 bf16x8 __attribute__((ext_vector_type(8)));
typedef __bf16 bf16x4 __attribute__((ext_vector_type(4)));
typedef float f32x4 __attribute__((ext_vector_type(4)));
typedef __bf16 bf16x8_a __attribute__((ext_vector_type(8), __may_alias__));
typedef __bf16 bf16_a __attribute__((__may_alias__));

constexpr int BATCH = 2;
constexpr int SEQ   = 2048;
constexpr int HID   = 2048;
constexpr int NHEAD = 16;
constexpr int NKV   = 8;
constexpr int HD    = 128;
constexpr int MROWS = BATCH * SEQ; // 4096

#define DEVINL __device__ __forceinline__

DEVINL void async16(void* l, const void* g) {
  __builtin_amdgcn_global_load_lds((const __attribute__((address_space(1))) void*)g,
                                   (__attribute__((address_space(3))) void*)l, 16, 0, 0);
}

DEVINL f32x4 mfma16(bf16x8 a, bf16x8 b, f32x4 c) {
  return __builtin_amdgcn_mfma_f32_16x16x32_bf16(a, b, c, 0, 0, 0);
}

DEVINL f32x4 fzero4() { f32x4 z; z[0] = 0.f; z[1] = 0.f; z[2] = 0.f; z[3] = 0.f; return z; }

DEVINL float ex2(float x) {
#if __has_builtin(__builtin_amdgcn_exp2f)
  return __builtin_amdgcn_exp2f(x);
#else
  return __expf(x * 0.6931471805599453f);
#endif
}
DEVINL float rcp1(float x) {
#if __has_builtin(__builtin_amdgcn_rcpf)
  return __builtin_amdgcn_rcpf(x);
#else
  return 1.0f / x;
#endif
}

// ---------------- elementwise cast f32 -> bf16 ----------------
__global__ __launch_bounds__(256) void cast_f32_bf16(const float* __restrict__ x,
                                                     bf16* __restrict__ y, int n) {
  int i = (blockIdx.x * 256 + threadIdx.x) * 4;
  if (i + 3 < n) {
    float4 v = *(const float4*)(x + i);
    bf16x4 o;
    o[0] = (bf16)v.x; o[1] = (bf16)v.y; o[2] = (bf16)v.z; o[3] = (bf16)v.w;
    *(bf16x4*)(y + i) = o;
  }
}

// ---------------- W transpose f32[K][N] -> bf16 WT[N][K] ----------------
__global__ __launch_bounds__(256) void wtrans(const float* __restrict__ W,
                                              bf16* __restrict__ WT, int K, int N) {
  __shared__ bf16 t[64][65];
  int n0 = blockIdx.x * 64, k0 = blockIdx.y * 64;
  for (int i = threadIdx.x; i < 4096; i += 256) {
    int r = i >> 6, c = i & 63;
    t[r][c] = (bf16)W[(size_t)(k0 + r) * N + n0 + c];
  }
  __syncthreads();
  for (int i = threadIdx.x; i < 4096; i += 256) {
    int r = i >> 6, c = i & 63;
    WT[(size_t)(n0 + r) * K + k0 + c] = t[c][r];
  }
}

// ---------------- V[b*S+s][kvh*128+d] -> VT[(b*8+kvh)*128+d][s] ----------------
__global__ __launch_bounds__(256) void vtrans(const bf16* __restrict__ V, bf16* __restrict__ VT) {
  __shared__ bf16 t[64][65];
  int s0 = blockIdx.x * 64, d0 = blockIdx.y * 64;
  int bh = blockIdx.z, b = bh >> 3, kvh = bh & 7;
  for (int i = threadIdx.x; i < 4096; i += 256) {
    int r = i >> 6, c = i & 63;
    t[r][c] = V[(size_t)(b * SEQ + s0 + r) * (NKV * HD) + kvh * HD + d0 + c];
  }
  __syncthreads();
  for (int i = threadIdx.x; i < 4096; i += 256) {
    int r = i >> 6, c = i & 63;
    VT[((size_t)bh * HD + d0 + r) * SEQ + s0 + c] = t[c][r];
  }
}

// ---------------- RoPE tables: cos/sin [SEQ][64] ----------------
__global__ void rope_tab(float* __restrict__ ct, float* __restrict__ st) {
  int s = blockIdx.x, d = threadIdx.x;
  float freq = powf(10000.0f, -(float)d * (1.0f / 64.0f));
  float a = (float)s * freq;
  ct[s * 64 + d] = cosf(a);
  st[s * 64 + d] = sinf(a);
}

// ---------------- GEMM: C = A[M,K] @ BT[N,K]^T ----------------
template <int EPI>
__global__ __launch_bounds__(256) void gemm_bf16k(const bf16* __restrict__ A,
                                                  const bf16* __restrict__ BT,
                                                  void* __restrict__ Cout, int M, int N, int K,
                                                  const float* __restrict__ ct,
                                                  const float* __restrict__ st) {
  __shared__ alignas(16) char ldsA[16384];
  __shared__ alignas(16) char ldsB[16384];
  const int tid = threadIdx.x;
  const int lane = tid & 63;
  const int w = tid >> 6;
  const int l15 = lane & 15;
  const int l4 = lane >> 4;
  const int gx = gridDim.x;
  const int nwg = gx * gridDim.y;
  int id = blockIdx.y * gx + blockIdx.x;
  id = (id & 7) * (nwg >> 3) + (id >> 3);
  const int row0 = (id / gx) * 128;
  const int col0 = (id % gx) * 128;

  f32x4 acc[2][8];
#pragma unroll
  for (int mt = 0; mt < 2; mt++)
#pragma unroll
    for (int nt = 0; nt < 8; nt++) acc[mt][nt] = fzero4();

  const int ciB = w * 64 + lane;
  const int nk = K >> 6;
  for (int kt = 0; kt < nk; ++kt) {
    const int k0 = kt << 6;
    __syncthreads();
#pragma unroll
    for (int j = 0; j < 4; j++) {
      int ci = j * 256 + ciB;
      int r = ci >> 3, ps = ci & 7, ls = ps ^ (r & 7);
      char* dstA = ldsA + (j * 256 + w * 64) * 16;
      char* dstB = ldsB + (j * 256 + w * 64) * 16;
      async16(dstA, A + (size_t)(row0 + r) * K + k0 + ls * 8);
      async16(dstB, BT + (size_t)(col0 + r) * K + k0 + ls * 8);
    }
    asm volatile("s_waitcnt vmcnt(0)" ::: "memory");
    __syncthreads();

    bf16x8 af[2][2];
#pragma unroll
    for (int mt = 0; mt < 2; mt++)
#pragma unroll
      for (int kc = 0; kc < 2; kc++) {
        int r = w * 32 + mt * 16 + l15;
        int off = ((r << 7) + ((kc * 4 + l4) << 4)) ^ ((r & 7) << 4);
        af[mt][kc] = *(const bf16x8_a*)(ldsA + off);
      }
#pragma unroll
    for (int nt = 0; nt < 8; nt++) {
#pragma unroll
      for (int kc = 0; kc < 2; kc++) {
        int r = nt * 16 + l15;
        int off = ((r << 7) + ((kc * 4 + l4) << 4)) ^ ((r & 7) << 4);
        bf16x8 bfr = *(const bf16x8_a*)(ldsB + off);
        acc[0][nt] = mfma16(af[0][kc], bfr, acc[0][nt]);
        acc[1][nt] = mfma16(af[1][kc], bfr, acc[1][nt]);
      }
    }
  }

#pragma unroll
  for (int mt = 0; mt < 2; mt++)
#pragma unroll
    for (int nt = 0; nt < 8; nt++)
#pragma unroll
      for (int rg = 0; rg < 4; rg++) {
        int row = row0 + w * 32 + mt * 16 + l4 * 4 + rg;
        int col = col0 + nt * 16 + l15;
        float v = acc[mt][nt][rg];
        if (EPI == 2) {
          ((float*)Cout)[(size_t)row * N + col] = v;
        } else if (EPI == 0) {
          ((bf16*)Cout)[(size_t)row * N + col] = (bf16)v;
        } else {
          int d = col & 127;
          int s = row & (SEQ - 1);
          int ntp = (nt < 4) ? nt + 4 : nt - 4;
          float pv = (nt < 4) ? -acc[mt][ntp][rg] : acc[mt][ntp][rg];
          float cc = ct[s * 64 + (d & 63)];
          float ss = st[s * 64 + (d & 63)];
          ((bf16*)Cout)[(size_t)row * N + col] = (bf16)(v * cc + pv * ss);
        }
      }
}

// ---------------- Flash attention v3 ----------------
// grid (qt=16, h=16, b=2) swizzled, 256 thr / 4 waves; wave = 32 q-rows.
// K/V double-buffered in swizzled LDS via global_load_lds (2-phase pipeline:
// stage(next) issued first, one vmcnt(0)+barrier per tile). Fixed-max softcap
// softmax (scores bounded to +/-50 -> no online max). P via per-wave LDS.
__global__ __launch_bounds__(256, 2) void attn3(const bf16* __restrict__ Q,
                                                const bf16* __restrict__ Kg,
                                                const bf16* __restrict__ VTg,
                                                bf16* __restrict__ O) {
  __shared__ alignas(16) char ldsK[32768];   // 2 x [64 kv][128 d] swizzled
  __shared__ alignas(16) char ldsV[32768];   // 2 x [128 d][64 kv] swizzled
  __shared__ alignas(16) char ldsP[16384];   // 4 waves x P[32][64]
  const int tid = threadIdx.x, lane = tid & 63, w = tid >> 6;
  const int l15 = lane & 15, l4 = lane >> 4;

  const int nx = gridDim.x, ny = gridDim.y;
  const int nwg = nx * ny * gridDim.z;  // 512
  int id = (blockIdx.z * ny + blockIdx.y) * nx + blockIdx.x;
  id = (id & 7) * (nwg >> 3) + (id >> 3);
  const int qt = id % nx; id /= nx;
  const int h = id % ny; const int b = id / ny;
  const int kvh = h >> 1;
  const int rowQ0 = b * SEQ + qt * 128 + w * 32;

  // Q A-fragments
  bf16x8 qf[2][4];
#pragma unroll
  for (int mt = 0; mt < 2; mt++)
#pragma unroll
    for (int kc = 0; kc < 4; kc++)
      qf[mt][kc] = *(const bf16x8_a*)(Q + (size_t)(rowQ0 + mt * 16 + l15) * (NHEAD * HD) +
                                      h * HD + kc * 32 + l4 * 8);

  f32x4 o[2][8];
#pragma unroll
  for (int mt = 0; mt < 2; mt++)
#pragma unroll
    for (int dt = 0; dt < 8; dt++) o[mt][dt] = fzero4();
  float lsum[2][4] = {{0.f, 0.f, 0.f, 0.f}, {0.f, 0.f, 0.f, 0.f}};

  // staging constants (linear LDS dest, inverse-swizzled global source)
  const int dstc = tid * 16;
  const int rK = tid >> 4, lsK = (tid & 15) ^ (rK & 7);
  const int rV = tid >> 3, lsV = (tid & 7) ^ (rV & 7);
  const size_t koff0 = (size_t)(b * SEQ + rK) * (NKV * HD) + kvh * HD + lsK * 8;
  const size_t voff0 = ((size_t)(b * NKV + kvh) * HD + rV) * SEQ + lsV * 8;

  char* myP = ldsP + w * 4096;
  const float C1 = 5.100874372587525e-3f;   // 2*log2e/(50*sqrt(128))
  const float C2 = -144.26950408889634f;    // -100*log2e
  const float C3 = 72.13475204444817f;      // 50*log2e

  auto STAGE = [&](int buf, int t) {
    char* dK = ldsK + buf * 16384 + dstc;
    char* dV = ldsV + buf * 16384 + dstc;
    const bf16* ks = Kg + koff0 + (size_t)t * (64 * NKV * HD);
    const bf16* vs = VTg + voff0 + (size_t)t * 64;
#pragma unroll
    for (int j = 0; j < 4; j++) async16(dK + j * 4096, ks + j * 16 * (NKV * HD));
#pragma unroll
    for (int j = 0; j < 4; j++) async16(dV + j * 4096, vs + (size_t)j * 32 * SEQ);
  };

  STAGE(0, 0);
  asm volatile("s_waitcnt vmcnt(0)" ::: "memory");
  __syncthreads();

  for (int t = 0; t < SEQ / 64; ++t) {
    const int cur = t & 1;
    STAGE(cur ^ 1, (t + 1) & (SEQ / 64 - 1));  // issue next-tile loads first

    const char* lK = ldsK + cur * 16384;
    const char* lV = ldsV + cur * 16384;

    // ---- QK^T: S[32 q][64 kv] ----
    f32x4 sc[2][4];
#pragma unroll
    for (int nt = 0; nt < 4; nt++) { sc[0][nt] = fzero4(); sc[1][nt] = fzero4(); }
    __builtin_amdgcn_s_setprio(1);
#pragma unroll
    for (int kc = 0; kc < 4; kc++) {
#pragma unroll
      for (int nt = 0; nt < 4; nt++) {
        int r = nt * 16 + l15;
        int off = ((r << 8) + ((kc * 4 + l4) << 4)) ^ ((r & 7) << 4);
        bf16x8 kf = *(const bf16x8_a*)(lK + off);
        sc[0][nt] = mfma16(qf[0][kc], kf, sc[0][nt]);
        sc[1][nt] = mfma16(qf[1][kc], kf, sc[1][nt]);
      }
    }
    __builtin_amdgcn_s_setprio(0);

    // ---- softcap + exp (fixed max) + P write ----
#pragma unroll
    for (int mt = 0; mt < 2; mt++)
#pragma unroll
      for (int rg = 0; rg < 4; rg++) {
        int pr = mt * 16 + l4 * 4 + rg;
#pragma unroll
        for (int nt = 0; nt < 4; nt++) {
          float s = sc[mt][nt][rg];
          float u = ex2(s * C1);
          float r = rcp1(1.0f + u);
          float p = ex2(fmaf(C2, r, C3));
          lsum[mt][rg] += p;
          int off = ((pr << 7) + ((nt * 16 + l15) << 1)) ^ ((pr & 7) << 4);
          *(bf16_a*)(myP + off) = (bf16)p;
        }
      }
    asm volatile("s_waitcnt lgkmcnt(0)" ::: "memory");

    // ---- PV: O += P[32 q][64 kv] @ V[64 kv][128 d] ----
    bf16x8 pa[2][2];
#pragma unroll
    for (int mt = 0; mt < 2; mt++)
#pragma unroll
      for (int kc = 0; kc < 2; kc++) {
        int r = mt * 16 + l15;
        int off = ((r << 7) + ((kc * 4 + l4) << 4)) ^ ((r & 7) << 4);
        pa[mt][kc] = *(const bf16x8_a*)(myP + off);
      }
    __builtin_amdgcn_s_setprio(1);
#pragma unroll
    for (int dt = 0; dt < 8; dt++) {
#pragma unroll
      for (int kc = 0; kc < 2; kc++) {
        int r = dt * 16 + l15;
        int off = ((r << 7) + ((kc * 4 + l4) << 4)) ^ ((r & 7) << 4);
        bf16x8 vf = *(const bf16x8_a*)(lV + off);
        o[0][dt] = mfma16(pa[0][kc], vf, o[0][dt]);
        o[1][dt] = mfma16(pa[1][kc], vf, o[1][dt]);
      }
    }
    __builtin_amdgcn_s_setprio(0);

    asm volatile("s_waitcnt vmcnt(0)" ::: "memory");  // next tile staged
    __syncthreads();
  }

  // final row-sum reduce across 16-lane column groups
#pragma unroll
  for (int mt = 0; mt < 2; mt++)
#pragma unroll
    for (int rg = 0; rg < 4; rg++) {
      float v = lsum[mt][rg];
      v += __shfl_xor(v, 1);
      v += __shfl_xor(v, 2);
      v += __shfl_xor(v, 4);
      v += __shfl_xor(v, 8);
      lsum[mt][rg] = 1.0f / v;
    }

#pragma unroll
  for (int mt = 0; mt < 2; mt++)
#pragma unroll
    for (int rg = 0; rg < 4; rg++) {
      int row = rowQ0 + mt * 16 + l4 * 4 + rg;
#pragma unroll
      for (int dt = 0; dt < 8; dt++) {
        int col = h * HD + dt * 16 + l15;
        O[(size_t)row * (NHEAD * HD) + col] = (bf16)(o[mt][dt][rg] * lsum[mt][rg]);
      }
    }
}

extern "C" void kernel_launch(void* const* d_in, const int* in_sizes, int n_in,
                              void* d_out, int out_size, void* d_ws, size_t ws_size,
                              hipStream_t stream) {
  const float* X  = (const float*)d_in[0];
  const float* Wq = (const float*)d_in[1];
  const float* Wk = (const float*)d_in[2];
  const float* Wv = (const float*)d_in[3];
  const float* Wo = (const float*)d_in[4];
  float* out = (float*)d_out;

  char* ws = (char*)d_ws;
  size_t off = 0;
  auto alloc = [&](size_t bytes) {
    void* p = ws + off;
    off += (bytes + 255) & ~(size_t)255;
    return p;
  };
  bf16* Xb  = (bf16*)alloc((size_t)MROWS * HID * 2);
  bf16* WqT = (bf16*)alloc((size_t)2048 * 2048 * 2);
  bf16* WkT = (bf16*)alloc((size_t)1024 * 2048 * 2);
  bf16* WvT = (bf16*)alloc((size_t)1024 * 2048 * 2);
  bf16* WoT = (bf16*)alloc((size_t)2048 * 2048 * 2);
  bf16* Qb  = (bf16*)alloc((size_t)MROWS * 2048 * 2);
  bf16* Kb  = (bf16*)alloc((size_t)MROWS * 1024 * 2);
  bf16* Vb  = (bf16*)alloc((size_t)MROWS * 1024 * 2);
  bf16* VTb = (bf16*)alloc((size_t)16 * 128 * 2048 * 2);
  bf16* AOb = (bf16*)alloc((size_t)MROWS * 2048 * 2);
  float* ct = (float*)alloc((size_t)SEQ * 64 * 4);
  float* st = (float*)alloc((size_t)SEQ * 64 * 4);

  cast_f32_bf16<<<(MROWS * HID) / 1024, 256, 0, stream>>>(X, Xb, MROWS * HID);
  wtrans<<<dim3(32, 32), 256, 0, stream>>>(Wq, WqT, 2048, 2048);
  wtrans<<<dim3(16, 32), 256, 0, stream>>>(Wk, WkT, 2048, 1024);
  wtrans<<<dim3(16, 32), 256, 0, stream>>>(Wv, WvT, 2048, 1024);
  wtrans<<<dim3(32, 32), 256, 0, stream>>>(Wo, WoT, 2048, 2048);
  rope_tab<<<SEQ, 64, 0, stream>>>(ct, st);
  gemm_bf16k<1><<<dim3(16, 32), 256, 0, stream>>>(Xb, WqT, Qb, MROWS, 2048, 2048, ct, st);
  gemm_bf16k<1><<<dim3(8, 32), 256, 0, stream>>>(Xb, WkT, Kb, MROWS, 1024, 2048, ct, st);
  gemm_bf16k<0><<<dim3(8, 32), 256, 0, stream>>>(Xb, WvT, Vb, MROWS, 1024, 2048, nullptr, nullptr);
  vtrans<<<dim3(32, 2, 16), 256, 0, stream>>>(Vb, VTb);
  attn3<<<dim3(16, 16, 2), 256, 0, stream>>>(Qb, Kb, VTb, AOb);
  gemm_bf16k<2><<<dim3(16, 32), 256, 0, stream>>>(AOb, WoT, out, MROWS, 2048, 2048, nullptr, nullptr);

  (void)in_sizes; (void)n_in; (void)out_size; (void)ws_size;
}

// Round 4
// 302.284 us; speedup vs baseline: 2.2422x; 1.0884x over previous
//
#include <hip/hip_runtime.h>
#include <math.h>

typedef __bf16 bf16;
typedef __bf16 bf16x8 __attribute__((ext_vector_type(8)));
typedef __bf16 bf16x4 __attribute__((ext_vector_type(4)));
typedef float f32x4 __attribute__((ext_vector_type(4)));
typedef __bf16 bf16x8_a __attribute__((ext_vector_type(8), __may_alias__));
typedef __bf16 bf16_a __attribute__((__may_alias__));

constexpr int BATCH = 2;
constexpr int SEQ   = 2048;
constexpr int HID   = 2048;
constexpr int NHEAD = 16;
constexpr int NKV   = 8;
constexpr int HD    = 128;
constexpr int MROWS = BATCH * SEQ; // 4096

#define DEVINL __device__ __forceinline__

DEVINL void async16(void* l, const void* g) {
  __builtin_amdgcn_global_load_lds((const __attribute__((address_space(1))) void*)g,
                                   (__attribute__((address_space(3))) void*)l, 16, 0, 0);
}

DEVINL f32x4 mfma16(bf16x8 a, bf16x8 b, f32x4 c) {
  return __builtin_amdgcn_mfma_f32_16x16x32_bf16(a, b, c, 0, 0, 0);
}

DEVINL f32x4 fzero4() { f32x4 z; z[0] = 0.f; z[1] = 0.f; z[2] = 0.f; z[3] = 0.f; return z; }

DEVINL float ex2(float x) {
#if __has_builtin(__builtin_amdgcn_exp2f)
  return __builtin_amdgcn_exp2f(x);
#else
  return __expf(x * 0.6931471805599453f);
#endif
}
DEVINL float rcp1(float x) {
#if __has_builtin(__builtin_amdgcn_rcpf)
  return __builtin_amdgcn_rcpf(x);
#else
  return 1.0f / x;
#endif
}

// ---------------- elementwise cast f32 -> bf16 ----------------
__global__ __launch_bounds__(256) void cast_f32_bf16(const float* __restrict__ x,
                                                     bf16* __restrict__ y, int n) {
  int i = (blockIdx.x * 256 + threadIdx.x) * 4;
  if (i + 3 < n) {
    float4 v = *(const float4*)(x + i);
    bf16x4 o;
    o[0] = (bf16)v.x; o[1] = (bf16)v.y; o[2] = (bf16)v.z; o[3] = (bf16)v.w;
    *(bf16x4*)(y + i) = o;
  }
}

// ---------------- all-W transpose f32[K][N] -> bf16 WT[N][K], K=2048 ----------------
__global__ __launch_bounds__(256) void wtrans4(const float* __restrict__ Wq,
                                               const float* __restrict__ Wk,
                                               const float* __restrict__ Wv,
                                               const float* __restrict__ Wo,
                                               bf16* __restrict__ WqT, bf16* __restrict__ WkT,
                                               bf16* __restrict__ WvT, bf16* __restrict__ WoT) {
  __shared__ bf16 t[64][65];
  const float* W; bf16* WT; int N;
  switch (blockIdx.z) {
    case 0: W = Wq; WT = WqT; N = 2048; break;
    case 1: W = Wk; WT = WkT; N = 1024; break;
    case 2: W = Wv; WT = WvT; N = 1024; break;
    default: W = Wo; WT = WoT; N = 2048; break;
  }
  int n0 = blockIdx.x * 64, k0 = blockIdx.y * 64;
  if (n0 >= N) return;
  for (int i = threadIdx.x; i < 4096; i += 256) {
    int r = i >> 6, c = i & 63;
    t[r][c] = (bf16)W[(size_t)(k0 + r) * N + n0 + c];
  }
  __syncthreads();
  for (int i = threadIdx.x; i < 4096; i += 256) {
    int r = i >> 6, c = i & 63;
    WT[(size_t)(n0 + r) * 2048 + k0 + c] = t[c][r];
  }
}

// ---------------- V[b*S+s][kvh*128+d] -> VT[(b*8+kvh)*128+d][s] ----------------
__global__ __launch_bounds__(256) void vtrans(const bf16* __restrict__ V, bf16* __restrict__ VT) {
  __shared__ bf16 t[64][65];
  int s0 = blockIdx.x * 64, d0 = blockIdx.y * 64;
  int bh = blockIdx.z, b = bh >> 3, kvh = bh & 7;
  for (int i = threadIdx.x; i < 4096; i += 256) {
    int r = i >> 6, c = i & 63;
    t[r][c] = V[(size_t)(b * SEQ + s0 + r) * (NKV * HD) + kvh * HD + d0 + c];
  }
  __syncthreads();
  for (int i = threadIdx.x; i < 4096; i += 256) {
    int r = i >> 6, c = i & 63;
    VT[((size_t)bh * HD + d0 + r) * SEQ + s0 + c] = t[c][r];
  }
}

// ---------------- RoPE tables: cos/sin [SEQ][64] ----------------
__global__ void rope_tab(float* __restrict__ ct, float* __restrict__ st) {
  int s = blockIdx.x, d = threadIdx.x;
  float freq = powf(10000.0f, -(float)d * (1.0f / 64.0f));
  float a = (float)s * freq;
  ct[s * 64 + d] = cosf(a);
  st[s * 64 + d] = sinf(a);
}

// ---------------- 256x256-tile 8-wave phase-split GEMM ----------------
// C = A[M,K] @ BT[N,K]^T.  512 thr = 8 waves (2M x 4N), wave tile 128x64.
// Wave's nt tile n-offset = wn*16 + nt*64 (RoPE +/-64 pairs in-wave for EPI 1).
// Per K-tile (BK=64): 4 barrier-free phases, snake quadrants; dbuf LDS;
// one vmcnt(0)+barrier per tile (drains loads issued a full tile earlier).
// EPI 1: fused QKV epilogue (rope Q->C0 s2048, rope K->C1 s1024, plain V->C2 s1024)
// EPI 2: f32 store to C0 stride N.
template <int EPI>
__global__ __launch_bounds__(512, 2) void gemm256(const bf16* __restrict__ A,
                                                  const bf16* __restrict__ BT,
                                                  void* __restrict__ C0, void* __restrict__ C1,
                                                  void* __restrict__ C2, int M, int N, int K,
                                                  const float* __restrict__ ct,
                                                  const float* __restrict__ st) {
  __shared__ alignas(16) char ldsA[65536];  // 2 bufs x 256 rows x 64k x bf16
  __shared__ alignas(16) char ldsB[65536];
  const int tid = threadIdx.x, lane = tid & 63, w = tid >> 6;
  const int l15 = lane & 15, l4 = lane >> 4;
  const int wm = w >> 2, wn = w & 3;
  const int gx = gridDim.x;
  const int nwg = gx * gridDim.y;
  int id = blockIdx.y * gx + blockIdx.x;
  id = (id & 7) * (nwg >> 3) + (id >> 3);
  const int row0 = (id / gx) * 256;
  const int col0 = (id % gx) * 256;

  f32x4 acc[8][4];
#pragma unroll
  for (int mt = 0; mt < 8; mt++)
#pragma unroll
    for (int nt = 0; nt < 4; nt++) acc[mt][nt] = fzero4();

  // staging granules: half-tile = 128 rows x 64 k = 1024 granules of 16B;
  // thread j in {0,1}: ci = j*512 + w*64 + lane
  const int ci0 = w * 64 + lane;
  const int rG0 = ci0 >> 3, sG0 = ((ci0 & 7) ^ (rG0 & 7)) * 8;
  const int ci1 = 512 + ci0;
  const int rG1 = ci1 >> 3, sG1 = ((ci1 & 7) ^ (rG1 & 7)) * 8;
  const int dst0 = (w * 64) * 16, dst1 = (512 + w * 64) * 16;

  const bf16* Asrc = A + (size_t)row0 * K;
  const bf16* Bsrc = BT + (size_t)col0 * K;

  const int nk = K >> 6;

#define STG_A(half, kt, buf)                                                     \
  {                                                                              \
    char* d = ldsA + (buf) * 32768 + (half) * 16384;                             \
    const bf16* s = Asrc + (size_t)((half) * 128) * K + (kt) * 64;               \
    async16(d + dst0, s + (size_t)rG0 * K + sG0);                                \
    async16(d + dst1, s + (size_t)rG1 * K + sG1);                                \
  }
#define STG_B(half, kt, buf)                                                     \
  {                                                                              \
    char* d = ldsB + (buf) * 32768 + (half) * 16384;                             \
    const bf16* s = Bsrc + (size_t)((half) * 128) * K + (kt) * 64;               \
    async16(d + dst0, s + (size_t)rG0 * K + sG0);                                \
    async16(d + dst1, s + (size_t)rG1 * K + sG1);                                \
  }

  // prologue: stage tile 0 into buf 0
  STG_A(0, 0, 0) STG_A(1, 0, 0) STG_B(0, 0, 0) STG_B(1, 0, 0)

  bf16x8 af[8];     // current A-half: 4 mt x 2 kc
  bf16x8 bfr[2][4]; // both B-halves: 2 nt x 2 kc each

  for (int t = 0; t < nk; ++t) {
    const int buf = t & 1;
    const char* bA = ldsA + buf * 32768;
    const char* bB = ldsB + buf * 32768;
    const bool stg = (t + 1) < nk;
    const int nbuf = buf ^ 1;

    asm volatile("s_waitcnt vmcnt(0)" ::: "memory");
    __syncthreads();

    // ---- phase 0: quadrant (qm0, qn0); read A-half0 + B-half0; stage A-half0(t+1)
    if (stg) STG_A(0, t + 1, nbuf)
#pragma unroll
    for (int mtp = 0; mtp < 4; mtp++)
#pragma unroll
      for (int kc = 0; kc < 2; kc++) {
        int r = wm * 128 + mtp * 16 + l15;
        int off = ((r << 7) + ((kc * 4 + l4) << 4)) ^ ((r & 7) << 4);
        af[mtp * 2 + kc] = *(const bf16x8_a*)(bA + off);
      }
#pragma unroll
    for (int ntp = 0; ntp < 2; ntp++)
#pragma unroll
      for (int kc = 0; kc < 2; kc++) {
        int c = wn * 16 + ntp * 64 + l15;
        int off = ((c << 7) + ((kc * 4 + l4) << 4)) ^ ((c & 7) << 4);
        bfr[0][ntp * 2 + kc] = *(const bf16x8_a*)(bB + off);
      }
    __builtin_amdgcn_s_setprio(1);
#pragma unroll
    for (int mtp = 0; mtp < 4; mtp++)
#pragma unroll
      for (int ntp = 0; ntp < 2; ntp++)
#pragma unroll
        for (int kc = 0; kc < 2; kc++)
          acc[mtp][ntp] = mfma16(af[mtp * 2 + kc], bfr[0][ntp * 2 + kc], acc[mtp][ntp]);
    __builtin_amdgcn_s_setprio(0);

    // ---- phase 1: quadrant (qm0, qn1); read B-half1; stage A-half1(t+1)
    if (stg) STG_A(1, t + 1, nbuf)
#pragma unroll
    for (int ntp = 0; ntp < 2; ntp++)
#pragma unroll
      for (int kc = 0; kc < 2; kc++) {
        int c = wn * 16 + (ntp + 2) * 64 + l15;
        int off = ((c << 7) + ((kc * 4 + l4) << 4)) ^ ((c & 7) << 4);
        bfr[1][ntp * 2 + kc] = *(const bf16x8_a*)(bB + off);
      }
    __builtin_amdgcn_s_setprio(1);
#pragma unroll
    for (int mtp = 0; mtp < 4; mtp++)
#pragma unroll
      for (int ntp = 0; ntp < 2; ntp++)
#pragma unroll
        for (int kc = 0; kc < 2; kc++)
          acc[mtp][ntp + 2] = mfma16(af[mtp * 2 + kc], bfr[1][ntp * 2 + kc], acc[mtp][ntp + 2]);
    __builtin_amdgcn_s_setprio(0);

    // ---- phase 2: quadrant (qm1, qn1); read A-half1; stage B-half0(t+1)
    if (stg) STG_B(0, t + 1, nbuf)
#pragma unroll
    for (int mtp = 0; mtp < 4; mtp++)
#pragma unroll
      for (int kc = 0; kc < 2; kc++) {
        int r = wm * 128 + 64 + mtp * 16 + l15;
        int off = ((r << 7) + ((kc * 4 + l4) << 4)) ^ ((r & 7) << 4);
        af[mtp * 2 + kc] = *(const bf16x8_a*)(bA + off);
      }
    __builtin_amdgcn_s_setprio(1);
#pragma unroll
    for (int mtp = 0; mtp < 4; mtp++)
#pragma unroll
      for (int ntp = 0; ntp < 2; ntp++)
#pragma unroll
        for (int kc = 0; kc < 2; kc++)
          acc[mtp + 4][ntp + 2] = mfma16(af[mtp * 2 + kc], bfr[1][ntp * 2 + kc], acc[mtp + 4][ntp + 2]);
    __builtin_amdgcn_s_setprio(0);

    // ---- phase 3: quadrant (qm1, qn0); reuse B-half0; stage B-half1(t+1)
    if (stg) STG_B(1, t + 1, nbuf)
    __builtin_amdgcn_s_setprio(1);
#pragma unroll
    for (int mtp = 0; mtp < 4; mtp++)
#pragma unroll
      for (int ntp = 0; ntp < 2; ntp++)
#pragma unroll
        for (int kc = 0; kc < 2; kc++)
          acc[mtp + 4][ntp] = mfma16(af[mtp * 2 + kc], bfr[0][ntp * 2 + kc], acc[mtp + 4][ntp]);
    __builtin_amdgcn_s_setprio(0);
  }
#undef STG_A
#undef STG_B

  // ---- epilogue ----
#pragma unroll
  for (int mt = 0; mt < 8; mt++)
#pragma unroll
    for (int nt = 0; nt < 4; nt++)
#pragma unroll
      for (int rg = 0; rg < 4; rg++) {
        int row = row0 + wm * 128 + mt * 16 + l4 * 4 + rg;
        int cl = col0 + wn * 16 + nt * 64 + l15;
        float v = acc[mt][nt][rg];
        if (EPI == 2) {
          ((float*)C0)[(size_t)row * N + cl] = v;
        } else {
          if (cl < 3072) {  // rope for Q and K ranges
            int s = row & (SEQ - 1);
            float cc = ct[s * 64 + wn * 16 + l15];
            float ss = st[s * 64 + wn * 16 + l15];
            float pv = acc[mt][nt ^ 1][rg];
            v = (nt & 1) ? fmaf(v, cc, pv * ss) : fmaf(v, cc, -pv * ss);
          }
          if (cl < 2048)
            ((bf16*)C0)[(size_t)row * 2048 + cl] = (bf16)v;
          else if (cl < 3072)
            ((bf16*)C1)[(size_t)row * 1024 + (cl - 2048)] = (bf16)v;
          else
            ((bf16*)C2)[(size_t)row * 1024 + (cl - 3072)] = (bf16)v;
        }
      }
}

// ---------------- Flash attention v3 (unchanged from R3) ----------------
__global__ __launch_bounds__(256, 2) void attn3(const bf16* __restrict__ Q,
                                                const bf16* __restrict__ Kg,
                                                const bf16* __restrict__ VTg,
                                                bf16* __restrict__ O) {
  __shared__ alignas(16) char ldsK[32768];
  __shared__ alignas(16) char ldsV[32768];
  __shared__ alignas(16) char ldsP[16384];
  const int tid = threadIdx.x, lane = tid & 63, w = tid >> 6;
  const int l15 = lane & 15, l4 = lane >> 4;

  const int nx = gridDim.x, ny = gridDim.y;
  const int nwg = nx * ny * gridDim.z;
  int id = (blockIdx.z * ny + blockIdx.y) * nx + blockIdx.x;
  id = (id & 7) * (nwg >> 3) + (id >> 3);
  const int qt = id % nx; id /= nx;
  const int h = id % ny; const int b = id / ny;
  const int kvh = h >> 1;
  const int rowQ0 = b * SEQ + qt * 128 + w * 32;

  bf16x8 qf[2][4];
#pragma unroll
  for (int mt = 0; mt < 2; mt++)
#pragma unroll
    for (int kc = 0; kc < 4; kc++)
      qf[mt][kc] = *(const bf16x8_a*)(Q + (size_t)(rowQ0 + mt * 16 + l15) * (NHEAD * HD) +
                                      h * HD + kc * 32 + l4 * 8);

  f32x4 o[2][8];
#pragma unroll
  for (int mt = 0; mt < 2; mt++)
#pragma unroll
    for (int dt = 0; dt < 8; dt++) o[mt][dt] = fzero4();
  float lsum[2][4] = {{0.f, 0.f, 0.f, 0.f}, {0.f, 0.f, 0.f, 0.f}};

  const int dstc = tid * 16;
  const int rK = tid >> 4, lsK = (tid & 15) ^ (rK & 7);
  const int rV = tid >> 3, lsV = (tid & 7) ^ (rV & 7);
  const size_t koff0 = (size_t)(b * SEQ + rK) * (NKV * HD) + kvh * HD + lsK * 8;
  const size_t voff0 = ((size_t)(b * NKV + kvh) * HD + rV) * SEQ + lsV * 8;

  char* myP = ldsP + w * 4096;
  const float C1 = 5.100874372587525e-3f;
  const float C2 = -144.26950408889634f;
  const float C3 = 72.13475204444817f;

  auto STAGE = [&](int buf, int t) {
    char* dK = ldsK + buf * 16384 + dstc;
    char* dV = ldsV + buf * 16384 + dstc;
    const bf16* ks = Kg + koff0 + (size_t)t * (64 * NKV * HD);
    const bf16* vs = VTg + voff0 + (size_t)t * 64;
#pragma unroll
    for (int j = 0; j < 4; j++) async16(dK + j * 4096, ks + j * 16 * (NKV * HD));
#pragma unroll
    for (int j = 0; j < 4; j++) async16(dV + j * 4096, vs + (size_t)j * 32 * SEQ);
  };

  STAGE(0, 0);
  asm volatile("s_waitcnt vmcnt(0)" ::: "memory");
  __syncthreads();

  for (int t = 0; t < SEQ / 64; ++t) {
    const int cur = t & 1;
    STAGE(cur ^ 1, (t + 1) & (SEQ / 64 - 1));

    const char* lK = ldsK + cur * 16384;
    const char* lV = ldsV + cur * 16384;

    f32x4 sc[2][4];
#pragma unroll
    for (int nt = 0; nt < 4; nt++) { sc[0][nt] = fzero4(); sc[1][nt] = fzero4(); }
    __builtin_amdgcn_s_setprio(1);
#pragma unroll
    for (int kc = 0; kc < 4; kc++) {
#pragma unroll
      for (int nt = 0; nt < 4; nt++) {
        int r = nt * 16 + l15;
        int off = ((r << 8) + ((kc * 4 + l4) << 4)) ^ ((r & 7) << 4);
        bf16x8 kf = *(const bf16x8_a*)(lK + off);
        sc[0][nt] = mfma16(qf[0][kc], kf, sc[0][nt]);
        sc[1][nt] = mfma16(qf[1][kc], kf, sc[1][nt]);
      }
    }
    __builtin_amdgcn_s_setprio(0);

#pragma unroll
    for (int mt = 0; mt < 2; mt++)
#pragma unroll
      for (int rg = 0; rg < 4; rg++) {
        int pr = mt * 16 + l4 * 4 + rg;
#pragma unroll
        for (int nt = 0; nt < 4; nt++) {
          float s = sc[mt][nt][rg];
          float u = ex2(s * C1);
          float r = rcp1(1.0f + u);
          float p = ex2(fmaf(C2, r, C3));
          lsum[mt][rg] += p;
          int off = ((pr << 7) + ((nt * 16 + l15) << 1)) ^ ((pr & 7) << 4);
          *(bf16_a*)(myP + off) = (bf16)p;
        }
      }
    asm volatile("s_waitcnt lgkmcnt(0)" ::: "memory");

    bf16x8 pa[2][2];
#pragma unroll
    for (int mt = 0; mt < 2; mt++)
#pragma unroll
      for (int kc = 0; kc < 2; kc++) {
        int r = mt * 16 + l15;
        int off = ((r << 7) + ((kc * 4 + l4) << 4)) ^ ((r & 7) << 4);
        pa[mt][kc] = *(const bf16x8_a*)(myP + off);
      }
    __builtin_amdgcn_s_setprio(1);
#pragma unroll
    for (int dt = 0; dt < 8; dt++) {
#pragma unroll
      for (int kc = 0; kc < 2; kc++) {
        int r = dt * 16 + l15;
        int off = ((r << 7) + ((kc * 4 + l4) << 4)) ^ ((r & 7) << 4);
        bf16x8 vf = *(const bf16x8_a*)(lV + off);
        o[0][dt] = mfma16(pa[0][kc], vf, o[0][dt]);
        o[1][dt] = mfma16(pa[1][kc], vf, o[1][dt]);
      }
    }
    __builtin_amdgcn_s_setprio(0);

    asm volatile("s_waitcnt vmcnt(0)" ::: "memory");
    __syncthreads();
  }

#pragma unroll
  for (int mt = 0; mt < 2; mt++)
#pragma unroll
    for (int rg = 0; rg < 4; rg++) {
      float v = lsum[mt][rg];
      v += __shfl_xor(v, 1);
      v += __shfl_xor(v, 2);
      v += __shfl_xor(v, 4);
      v += __shfl_xor(v, 8);
      lsum[mt][rg] = 1.0f / v;
    }

#pragma unroll
  for (int mt = 0; mt < 2; mt++)
#pragma unroll
    for (int rg = 0; rg < 4; rg++) {
      int row = rowQ0 + mt * 16 + l4 * 4 + rg;
#pragma unroll
      for (int dt = 0; dt < 8; dt++) {
        int col = h * HD + dt * 16 + l15;
        O[(size_t)row * (NHEAD * HD) + col] = (bf16)(o[mt][dt][rg] * lsum[mt][rg]);
      }
    }
}

extern "C" void kernel_launch(void* const* d_in, const int* in_sizes, int n_in,
                              void* d_out, int out_size, void* d_ws, size_t ws_size,
                              hipStream_t stream) {
  const float* X  = (const float*)d_in[0];
  const float* Wq = (const float*)d_in[1];
  const float* Wk = (const float*)d_in[2];
  const float* Wv = (const float*)d_in[3];
  const float* Wo = (const float*)d_in[4];
  float* out = (float*)d_out;

  char* ws = (char*)d_ws;
  size_t off = 0;
  auto alloc = [&](size_t bytes) {
    void* p = ws + off;
    off += (bytes + 255) & ~(size_t)255;
    return p;
  };
  bf16* Xb  = (bf16*)alloc((size_t)MROWS * HID * 2);
  // WqT/WkT/WvT adjacent & contiguous -> fused BT [4096][2048]
  bf16* WqT = (bf16*)alloc((size_t)2048 * 2048 * 2);
  bf16* WkT = (bf16*)alloc((size_t)1024 * 2048 * 2);
  bf16* WvT = (bf16*)alloc((size_t)1024 * 2048 * 2);
  bf16* WoT = (bf16*)alloc((size_t)2048 * 2048 * 2);
  bf16* Qb  = (bf16*)alloc((size_t)MROWS * 2048 * 2);
  bf16* Kb  = (bf16*)alloc((size_t)MROWS * 1024 * 2);
  bf16* Vb  = (bf16*)alloc((size_t)MROWS * 1024 * 2);
  bf16* VTb = (bf16*)alloc((size_t)16 * 128 * 2048 * 2);
  bf16* AOb = (bf16*)alloc((size_t)MROWS * 2048 * 2);
  float* ct = (float*)alloc((size_t)SEQ * 64 * 4);
  float* st = (float*)alloc((size_t)SEQ * 64 * 4);

  cast_f32_bf16<<<(MROWS * HID) / 1024, 256, 0, stream>>>(X, Xb, MROWS * HID);
  wtrans4<<<dim3(32, 32, 4), 256, 0, stream>>>(Wq, Wk, Wv, Wo, WqT, WkT, WvT, WoT);
  rope_tab<<<SEQ, 64, 0, stream>>>(ct, st);
  // fused QKV projection: N = 2048 + 1024 + 1024 = 4096
  gemm256<1><<<dim3(16, 16), 512, 0, stream>>>(Xb, WqT, Qb, Kb, Vb, MROWS, 4096, 2048, ct, st);
  vtrans<<<dim3(32, 2, 16), 256, 0, stream>>>(Vb, VTb);
  attn3<<<dim3(16, 16, 2), 256, 0, stream>>>(Qb, Kb, VTb, AOb);
  gemm256<2><<<dim3(8, 16), 512, 0, stream>>>(AOb, WoT, out, nullptr, nullptr, MROWS, 2048, 2048,
                                              nullptr, nullptr);

  (void)in_sizes; (void)n_in; (void)out_size; (void)ws_size;
}

// Round 5
// 292.560 us; speedup vs baseline: 2.3167x; 1.0332x over previous
//
#include <hip/hip_runtime.h>
#include <math.h>

typedef __bf16 bf16;
typedef __bf16 bf16x8 __attribute__((ext_vector_type(8)));
typedef __bf16 bf16x4 __attribute__((ext_vector_type(4)));
typedef float f32x4 __attribute__((ext_vector_type(4)));
typedef float f32x16 __attribute__((ext_vector_type(16)));
typedef unsigned int uint;
typedef uint u32x4 __attribute__((ext_vector_type(4)));
typedef uint u32x2 __attribute__((ext_vector_type(2)));
typedef __bf16 bf16x8_a __attribute__((ext_vector_type(8), __may_alias__));
typedef uint u32x2_a __attribute__((ext_vector_type(2), __may_alias__));
typedef __bf16 bf16_a __attribute__((__may_alias__));

constexpr int BATCH = 2;
constexpr int SEQ   = 2048;
constexpr int HID   = 2048;
constexpr int NHEAD = 16;
constexpr int NKV   = 8;
constexpr int HD    = 128;
constexpr int MROWS = BATCH * SEQ; // 4096

#define DEVINL __device__ __forceinline__

DEVINL void async16(void* l, const void* g) {
  __builtin_amdgcn_global_load_lds((const __attribute__((address_space(1))) void*)g,
                                   (__attribute__((address_space(3))) void*)l, 16, 0, 0);
}

DEVINL f32x4 mfma16(bf16x8 a, bf16x8 b, f32x4 c) {
  return __builtin_amdgcn_mfma_f32_16x16x32_bf16(a, b, c, 0, 0, 0);
}
DEVINL f32x16 mfma32(bf16x8 a, bf16x8 b, f32x16 c) {
  return __builtin_amdgcn_mfma_f32_32x32x16_bf16(a, b, c, 0, 0, 0);
}

DEVINL f32x4 fzero4() { f32x4 z; z[0] = 0.f; z[1] = 0.f; z[2] = 0.f; z[3] = 0.f; return z; }

DEVINL float ex2(float x) {
#if __has_builtin(__builtin_amdgcn_exp2f)
  return __builtin_amdgcn_exp2f(x);
#else
  return __expf(x * 0.6931471805599453f);
#endif
}

DEVINL uint pkbf16(float lo, float hi) {
  unsigned short l = __builtin_bit_cast(unsigned short, (bf16)lo);
  unsigned short h = __builtin_bit_cast(unsigned short, (bf16)hi);
  return (uint)l | ((uint)h << 16);
}

// ---------------- elementwise cast f32 -> bf16 ----------------
__global__ __launch_bounds__(256) void cast_f32_bf16(const float* __restrict__ x,
                                                     bf16* __restrict__ y, int n) {
  int i = (blockIdx.x * 256 + threadIdx.x) * 4;
  if (i + 3 < n) {
    float4 v = *(const float4*)(x + i);
    bf16x4 o;
    o[0] = (bf16)v.x; o[1] = (bf16)v.y; o[2] = (bf16)v.z; o[3] = (bf16)v.w;
    *(bf16x4*)(y + i) = o;
  }
}

// ---------------- all-W transpose f32[K][N] -> bf16 WT[N][K], K=2048 ----------------
__global__ __launch_bounds__(256) void wtrans4(const float* __restrict__ Wq,
                                               const float* __restrict__ Wk,
                                               const float* __restrict__ Wv,
                                               const float* __restrict__ Wo,
                                               bf16* __restrict__ WqT, bf16* __restrict__ WkT,
                                               bf16* __restrict__ WvT, bf16* __restrict__ WoT) {
  __shared__ bf16 t[64][65];
  const float* W; bf16* WT; int N;
  switch (blockIdx.z) {
    case 0: W = Wq; WT = WqT; N = 2048; break;
    case 1: W = Wk; WT = WkT; N = 1024; break;
    case 2: W = Wv; WT = WvT; N = 1024; break;
    default: W = Wo; WT = WoT; N = 2048; break;
  }
  int n0 = blockIdx.x * 64, k0 = blockIdx.y * 64;
  if (n0 >= N) return;
  for (int i = threadIdx.x; i < 4096; i += 256) {
    int r = i >> 6, c = i & 63;
    t[r][c] = (bf16)W[(size_t)(k0 + r) * N + n0 + c];
  }
  __syncthreads();
  for (int i = threadIdx.x; i < 4096; i += 256) {
    int r = i >> 6, c = i & 63;
    WT[(size_t)(n0 + r) * 2048 + k0 + c] = t[c][r];
  }
}

// ---------------- V[b*S+s][kvh*128+d] -> VT[(b*8+kvh)*128+d][s] ----------------
__global__ __launch_bounds__(256) void vtrans(const bf16* __restrict__ V, bf16* __restrict__ VT) {
  __shared__ bf16 t[64][65];
  int s0 = blockIdx.x * 64, d0 = blockIdx.y * 64;
  int bh = blockIdx.z, b = bh >> 3, kvh = bh & 7;
  for (int i = threadIdx.x; i < 4096; i += 256) {
    int r = i >> 6, c = i & 63;
    t[r][c] = V[(size_t)(b * SEQ + s0 + r) * (NKV * HD) + kvh * HD + d0 + c];
  }
  __syncthreads();
  for (int i = threadIdx.x; i < 4096; i += 256) {
    int r = i >> 6, c = i & 63;
    VT[((size_t)bh * HD + d0 + r) * SEQ + s0 + c] = t[c][r];
  }
}

// ---------------- RoPE tables: cos/sin [SEQ][64] ----------------
__global__ void rope_tab(float* __restrict__ ct, float* __restrict__ st) {
  int s = blockIdx.x, d = threadIdx.x;
  float freq = powf(10000.0f, -(float)d * (1.0f / 64.0f));
  float a = (float)s * freq;
  ct[s * 64 + d] = cosf(a);
  st[s * 64 + d] = sinf(a);
}

// ---------------- 256x256-tile 8-wave phase-split GEMM (unchanged from R4) ----------------
template <int EPI>
__global__ __launch_bounds__(512, 2) void gemm256(const bf16* __restrict__ A,
                                                  const bf16* __restrict__ BT,
                                                  void* __restrict__ C0, void* __restrict__ C1,
                                                  void* __restrict__ C2, int M, int N, int K,
                                                  const float* __restrict__ ct,
                                                  const float* __restrict__ st) {
  __shared__ alignas(16) char ldsA[65536];
  __shared__ alignas(16) char ldsB[65536];
  const int tid = threadIdx.x, lane = tid & 63, w = tid >> 6;
  const int l15 = lane & 15, l4 = lane >> 4;
  const int wm = w >> 2, wn = w & 3;
  const int gx = gridDim.x;
  const int nwg = gx * gridDim.y;
  int id = blockIdx.y * gx + blockIdx.x;
  id = (id & 7) * (nwg >> 3) + (id >> 3);
  const int row0 = (id / gx) * 256;
  const int col0 = (id % gx) * 256;

  f32x4 acc[8][4];
#pragma unroll
  for (int mt = 0; mt < 8; mt++)
#pragma unroll
    for (int nt = 0; nt < 4; nt++) acc[mt][nt] = fzero4();

  const int ci0 = w * 64 + lane;
  const int rG0 = ci0 >> 3, sG0 = ((ci0 & 7) ^ (rG0 & 7)) * 8;
  const int ci1 = 512 + ci0;
  const int rG1 = ci1 >> 3, sG1 = ((ci1 & 7) ^ (rG1 & 7)) * 8;
  const int dst0 = (w * 64) * 16, dst1 = (512 + w * 64) * 16;

  const bf16* Asrc = A + (size_t)row0 * K;
  const bf16* Bsrc = BT + (size_t)col0 * K;

  const int nk = K >> 6;

#define STG_A(half, kt, buf)                                                     \
  {                                                                              \
    char* d = ldsA + (buf) * 32768 + (half) * 16384;                             \
    const bf16* s = Asrc + (size_t)((half) * 128) * K + (kt) * 64;               \
    async16(d + dst0, s + (size_t)rG0 * K + sG0);                                \
    async16(d + dst1, s + (size_t)rG1 * K + sG1);                                \
  }
#define STG_B(half, kt, buf)                                                     \
  {                                                                              \
    char* d = ldsB + (buf) * 32768 + (half) * 16384;                             \
    const bf16* s = Bsrc + (size_t)((half) * 128) * K + (kt) * 64;               \
    async16(d + dst0, s + (size_t)rG0 * K + sG0);                                \
    async16(d + dst1, s + (size_t)rG1 * K + sG1);                                \
  }

  STG_A(0, 0, 0) STG_A(1, 0, 0) STG_B(0, 0, 0) STG_B(1, 0, 0)

  bf16x8 af[8];
  bf16x8 bfr[2][4];

  for (int t = 0; t < nk; ++t) {
    const int buf = t & 1;
    const char* bA = ldsA + buf * 32768;
    const char* bB = ldsB + buf * 32768;
    const bool stg = (t + 1) < nk;
    const int nbuf = buf ^ 1;

    asm volatile("s_waitcnt vmcnt(0)" ::: "memory");
    __syncthreads();

    if (stg) STG_A(0, t + 1, nbuf)
#pragma unroll
    for (int mtp = 0; mtp < 4; mtp++)
#pragma unroll
      for (int kc = 0; kc < 2; kc++) {
        int r = wm * 128 + mtp * 16 + l15;
        int off = ((r << 7) + ((kc * 4 + l4) << 4)) ^ ((r & 7) << 4);
        af[mtp * 2 + kc] = *(const bf16x8_a*)(bA + off);
      }
#pragma unroll
    for (int ntp = 0; ntp < 2; ntp++)
#pragma unroll
      for (int kc = 0; kc < 2; kc++) {
        int c = wn * 16 + ntp * 64 + l15;
        int off = ((c << 7) + ((kc * 4 + l4) << 4)) ^ ((c & 7) << 4);
        bfr[0][ntp * 2 + kc] = *(const bf16x8_a*)(bB + off);
      }
    __builtin_amdgcn_s_setprio(1);
#pragma unroll
    for (int mtp = 0; mtp < 4; mtp++)
#pragma unroll
      for (int ntp = 0; ntp < 2; ntp++)
#pragma unroll
        for (int kc = 0; kc < 2; kc++)
          acc[mtp][ntp] = mfma16(af[mtp * 2 + kc], bfr[0][ntp * 2 + kc], acc[mtp][ntp]);
    __builtin_amdgcn_s_setprio(0);

    if (stg) STG_A(1, t + 1, nbuf)
#pragma unroll
    for (int ntp = 0; ntp < 2; ntp++)
#pragma unroll
      for (int kc = 0; kc < 2; kc++) {
        int c = wn * 16 + (ntp + 2) * 64 + l15;
        int off = ((c << 7) + ((kc * 4 + l4) << 4)) ^ ((c & 7) << 4);
        bfr[1][ntp * 2 + kc] = *(const bf16x8_a*)(bB + off);
      }
    __builtin_amdgcn_s_setprio(1);
#pragma unroll
    for (int mtp = 0; mtp < 4; mtp++)
#pragma unroll
      for (int ntp = 0; ntp < 2; ntp++)
#pragma unroll
        for (int kc = 0; kc < 2; kc++)
          acc[mtp][ntp + 2] = mfma16(af[mtp * 2 + kc], bfr[1][ntp * 2 + kc], acc[mtp][ntp + 2]);
    __builtin_amdgcn_s_setprio(0);

    if (stg) STG_B(0, t + 1, nbuf)
#pragma unroll
    for (int mtp = 0; mtp < 4; mtp++)
#pragma unroll
      for (int kc = 0; kc < 2; kc++) {
        int r = wm * 128 + 64 + mtp * 16 + l15;
        int off = ((r << 7) + ((kc * 4 + l4) << 4)) ^ ((r & 7) << 4);
        af[mtp * 2 + kc] = *(const bf16x8_a*)(bA + off);
      }
    __builtin_amdgcn_s_setprio(1);
#pragma unroll
    for (int mtp = 0; mtp < 4; mtp++)
#pragma unroll
      for (int ntp = 0; ntp < 2; ntp++)
#pragma unroll
        for (int kc = 0; kc < 2; kc++)
          acc[mtp + 4][ntp + 2] = mfma16(af[mtp * 2 + kc], bfr[1][ntp * 2 + kc], acc[mtp + 4][ntp + 2]);
    __builtin_amdgcn_s_setprio(0);

    if (stg) STG_B(1, t + 1, nbuf)
    __builtin_amdgcn_s_setprio(1);
#pragma unroll
    for (int mtp = 0; mtp < 4; mtp++)
#pragma unroll
      for (int ntp = 0; ntp < 2; ntp++)
#pragma unroll
        for (int kc = 0; kc < 2; kc++)
          acc[mtp + 4][ntp] = mfma16(af[mtp * 2 + kc], bfr[0][ntp * 2 + kc], acc[mtp + 4][ntp]);
    __builtin_amdgcn_s_setprio(0);
  }
#undef STG_A
#undef STG_B

#pragma unroll
  for (int mt = 0; mt < 8; mt++)
#pragma unroll
    for (int nt = 0; nt < 4; nt++)
#pragma unroll
      for (int rg = 0; rg < 4; rg++) {
        int row = row0 + wm * 128 + mt * 16 + l4 * 4 + rg;
        int cl = col0 + wn * 16 + nt * 64 + l15;
        float v = acc[mt][nt][rg];
        if (EPI == 2) {
          ((float*)C0)[(size_t)row * N + cl] = v;
        } else {
          if (cl < 3072) {
            int s = row & (SEQ - 1);
            float cc = ct[s * 64 + wn * 16 + l15];
            float ss = st[s * 64 + wn * 16 + l15];
            float pv = acc[mt][nt ^ 1][rg];
            v = (nt & 1) ? fmaf(v, cc, pv * ss) : fmaf(v, cc, -pv * ss);
          }
          if (cl < 2048)
            ((bf16*)C0)[(size_t)row * 2048 + cl] = (bf16)v;
          else if (cl < 3072)
            ((bf16*)C1)[(size_t)row * 1024 + (cl - 2048)] = (bf16)v;
          else
            ((bf16*)C2)[(size_t)row * 1024 + (cl - 3072)] = (bf16)v;
        }
      }
}

// ---------------- Flash attention v4: swapped 32x32 QK^T, in-register P ----------------
// grid (qt=16, h=16, b=2) swizzled, 256 thr / 4 waves; wave = 32 q-rows.
// K/V double-buffered swizzled LDS (2-phase). S^T = mfma32(K,Q): q = lane col ->
// softcap/exp in-register (poly-tanh, 1 trans/elem), P packed bf16 + shfl_xor(32)
// half-exchange -> PV B-frags in-register. O^T = mfma32(V^T, P); lsum lane-local.
__global__ __launch_bounds__(256, 2) void attn4(const bf16* __restrict__ Q,
                                                const bf16* __restrict__ Kg,
                                                const bf16* __restrict__ VTg,
                                                bf16* __restrict__ O) {
  __shared__ alignas(16) char ldsK[32768];   // 2 x [64 kv][128 d] swizzled
  __shared__ alignas(16) char ldsV[32768];   // 2 x [128 d][64 kv] swizzled
  const int tid = threadIdx.x, lane = tid & 63, w = tid >> 6;
  const int l31 = lane & 31, hl = lane >> 5;

  const int nx = gridDim.x, ny = gridDim.y;
  const int nwg = nx * ny * gridDim.z;  // 512
  int id = (blockIdx.z * ny + blockIdx.y) * nx + blockIdx.x;
  id = (id & 7) * (nwg >> 3) + (id >> 3);
  const int qt = id % nx; id /= nx;
  const int h = id % ny; const int b = id / ny;
  const int kvh = h >> 1;
  const int qrow = b * SEQ + qt * 128 + w * 32 + l31;

  // Q B-fragments: col=q=l31, k(d) = kc*16 + hl*8 + j
  bf16x8 qf[8];
  const bf16* qp = Q + (size_t)qrow * (NHEAD * HD) + h * HD + hl * 8;
#pragma unroll
  for (int kc = 0; kc < 8; kc++) qf[kc] = *(const bf16x8_a*)(qp + kc * 16);

  f32x16 oT[4];
#pragma unroll
  for (int dt = 0; dt < 4; dt++)
#pragma unroll
    for (int r = 0; r < 16; r++) oT[dt][r] = 0.f;
  float lsum = 0.f;

  // staging (linear LDS dest, inverse-swizzled global source) — same as R3
  const int dstc = tid * 16;
  const int rK = tid >> 4, lsK = (tid & 15) ^ (rK & 7);
  const int rV = tid >> 3, lsV = (tid & 7) ^ (rV & 7);
  const size_t koff0 = (size_t)(b * SEQ + rK) * (NKV * HD) + kvh * HD + lsK * 8;
  const size_t voff0 = ((size_t)(b * NKV + kvh) * HD + rV) * SEQ + lsV * 8;

  const float C1 = 1.7677669529663689e-3f;  // 1/(50*sqrt(128))
  const float CA = -0.33333333333f;         // tanh poly
  const float CB = 0.13333333333f;          // 2/15
  const float C2 = 72.13475204444817f;      // 50*log2(e)

  auto STAGE = [&](int buf, int t) {
    char* dK = ldsK + buf * 16384 + dstc;
    char* dV = ldsV + buf * 16384 + dstc;
    const bf16* ks = Kg + koff0 + (size_t)t * (64 * NKV * HD);
    const bf16* vs = VTg + voff0 + (size_t)t * 64;
#pragma unroll
    for (int j = 0; j < 4; j++) async16(dK + j * 4096, ks + j * 16 * (NKV * HD));
#pragma unroll
    for (int j = 0; j < 4; j++) async16(dV + j * 4096, vs + (size_t)j * 32 * SEQ);
  };

  STAGE(0, 0);
  asm volatile("s_waitcnt vmcnt(0)" ::: "memory");
  __syncthreads();

  for (int t = 0; t < SEQ / 64; ++t) {
    const int cur = t & 1;
    STAGE(cur ^ 1, (t + 1) & (SEQ / 64 - 1));  // issue next-tile loads first

    const char* lK = ldsK + cur * 16384;
    const char* lV = ldsV + cur * 16384;

    // ---- swapped QK^T: S^T[64 kv][32 q], rows=kv (K A-frag), cols=q ----
    f32x16 sc[2];
#pragma unroll
    for (int r = 0; r < 16; r++) { sc[0][r] = 0.f; sc[1][r] = 0.f; }
    const int kvr0 = l31;          // ntb 0 row
    const int kvr1 = 32 + l31;     // ntb 1 row
    __builtin_amdgcn_s_setprio(1);
#pragma unroll
    for (int kc = 0; kc < 8; kc++) {
      int slot = kc * 2 + hl;
      int off0 = ((kvr0 << 8) + (slot << 4)) ^ ((kvr0 & 7) << 4);
      int off1 = ((kvr1 << 8) + (slot << 4)) ^ ((kvr1 & 7) << 4);
      bf16x8 kf0 = *(const bf16x8_a*)(lK + off0);
      bf16x8 kf1 = *(const bf16x8_a*)(lK + off1);
      sc[0] = mfma32(kf0, qf[kc], sc[0]);
      sc[1] = mfma32(kf1, qf[kc], sc[1]);
    }
    __builtin_amdgcn_s_setprio(0);

    // ---- softcap+exp (poly tanh, fixed max) + pack + half-exchange + PV ----
#pragma unroll
    for (int ntb = 0; ntb < 2; ntb++) {
#pragma unroll
      for (int r = 0; r < 16; r++) {
        float z = sc[ntb][r] * C1;
        float z2 = z * z;
        float wv = fmaf(z2, fmaf(z2, CB, CA), 1.0f);
        float p = ex2(z * wv * C2);
        lsum += p;
        sc[ntb][r] = p;
      }
      uint u[4][2], us[4][2];
#pragma unroll
      for (int q4 = 0; q4 < 4; q4++)
#pragma unroll
        for (int c = 0; c < 2; c++) {
          u[q4][c] = pkbf16(sc[ntb][4 * q4 + 2 * c], sc[ntb][4 * q4 + 2 * c + 1]);
          us[q4][c] = __shfl_xor(u[q4][c], 32);
        }
      __builtin_amdgcn_s_setprio(1);
#pragma unroll
      for (int sub = 0; sub < 2; sub++) {
        u32x4 bu;
        bu[0] = hl ? us[2 * sub + 1][0] : u[2 * sub][0];
        bu[1] = hl ? us[2 * sub + 1][1] : u[2 * sub][1];
        bu[2] = hl ? u[2 * sub + 1][0] : us[2 * sub][0];
        bu[3] = hl ? u[2 * sub + 1][1] : us[2 * sub][1];
        bf16x8 pb = __builtin_bit_cast(bf16x8, bu);
        const int kvb = ntb * 2 + sub;
        const int slot = kvb * 2 + hl;
#pragma unroll
        for (int dt = 0; dt < 4; dt++) {
          int d = dt * 32 + l31;
          int off = ((d << 7) + (slot << 4)) ^ ((d & 7) << 4);
          bf16x8 vf = *(const bf16x8_a*)(lV + off);
          oT[dt] = mfma32(vf, pb, oT[dt]);
        }
      }
      __builtin_amdgcn_s_setprio(0);
    }

    asm volatile("s_waitcnt vmcnt(0)" ::: "memory");  // next tile staged
    __syncthreads();
  }

  // ---- epilogue: full row-sum (two lanes per q), normalize, store O ----
  float lsf = lsum + __shfl_xor(lsum, 32);
  float inv = 1.0f / lsf;
  bf16* ob = O + (size_t)qrow * (NHEAD * HD) + h * HD;
#pragma unroll
  for (int dt = 0; dt < 4; dt++)
#pragma unroll
    for (int g = 0; g < 4; g++) {
      // d = dt*32 + 8*g + 4*hl + {0,1,2,3}  (from 32x32 C-layout rows)
      u32x2 pr;
      pr[0] = pkbf16(oT[dt][4 * g] * inv, oT[dt][4 * g + 1] * inv);
      pr[1] = pkbf16(oT[dt][4 * g + 2] * inv, oT[dt][4 * g + 3] * inv);
      *(u32x2_a*)(ob + dt * 32 + 8 * g + 4 * hl) = pr;
    }
}

extern "C" void kernel_launch(void* const* d_in, const int* in_sizes, int n_in,
                              void* d_out, int out_size, void* d_ws, size_t ws_size,
                              hipStream_t stream) {
  const float* X  = (const float*)d_in[0];
  const float* Wq = (const float*)d_in[1];
  const float* Wk = (const float*)d_in[2];
  const float* Wv = (const float*)d_in[3];
  const float* Wo = (const float*)d_in[4];
  float* out = (float*)d_out;

  char* ws = (char*)d_ws;
  size_t off = 0;
  auto alloc = [&](size_t bytes) {
    void* p = ws + off;
    off += (bytes + 255) & ~(size_t)255;
    return p;
  };
  bf16* Xb  = (bf16*)alloc((size_t)MROWS * HID * 2);
  // WqT/WkT/WvT adjacent & contiguous -> fused BT [4096][2048]
  bf16* WqT = (bf16*)alloc((size_t)2048 * 2048 * 2);
  bf16* WkT = (bf16*)alloc((size_t)1024 * 2048 * 2);
  bf16* WvT = (bf16*)alloc((size_t)1024 * 2048 * 2);
  bf16* WoT = (bf16*)alloc((size_t)2048 * 2048 * 2);
  bf16* Qb  = (bf16*)alloc((size_t)MROWS * 2048 * 2);
  bf16* Kb  = (bf16*)alloc((size_t)MROWS * 1024 * 2);
  bf16* Vb  = (bf16*)alloc((size_t)MROWS * 1024 * 2);
  bf16* VTb = (bf16*)alloc((size_t)16 * 128 * 2048 * 2);
  bf16* AOb = (bf16*)alloc((size_t)MROWS * 2048 * 2);
  float* ct = (float*)alloc((size_t)SEQ * 64 * 4);
  float* st = (float*)alloc((size_t)SEQ * 64 * 4);

  cast_f32_bf16<<<(MROWS * HID) / 1024, 256, 0, stream>>>(X, Xb, MROWS * HID);
  wtrans4<<<dim3(32, 32, 4), 256, 0, stream>>>(Wq, Wk, Wv, Wo, WqT, WkT, WvT, WoT);
  rope_tab<<<SEQ, 64, 0, stream>>>(ct, st);
  gemm256<1><<<dim3(16, 16), 512, 0, stream>>>(Xb, WqT, Qb, Kb, Vb, MROWS, 4096, 2048, ct, st);
  vtrans<<<dim3(32, 2, 16), 256, 0, stream>>>(Vb, VTb);
  attn4<<<dim3(16, 16, 2), 256, 0, stream>>>(Qb, Kb, VTb, AOb);
  gemm256<2><<<dim3(8, 16), 512, 0, stream>>>(AOb, WoT, out, nullptr, nullptr, MROWS, 2048, 2048,
                                              nullptr, nullptr);

  (void)in_sizes; (void)n_in; (void)out_size; (void)ws_size;
}